// Round 12
// baseline (161.845 us; speedup 1.0000x reference)
//
#include <hip/hip_runtime.h>

#define EPS_F 1e-6f
#define BLK   256

typedef float v4f __attribute__((ext_vector_type(4)));

// ---- Kernel 1: w = sigmoid(w_raw), 19x19 = 361 floats into d_ws ----
__global__ void sigmoid_w_kernel(const float* __restrict__ w_raw,
                                 float* __restrict__ w) {
    int i = threadIdx.x;
    if (i < 361) {
        w[i] = 1.0f / (1.0f + expf(-w_raw[i]));
    }
}

__device__ __forceinline__ float mixf(float a, float b, float wv) {
    float mn = fminf(a, b);
    float mx = fmaxf(a, b);
    return fmaf(wv, mn - mx, mx);   // w*mn + (1-w)*mx
}

__device__ __forceinline__ float clampf(float r) {
    return __builtin_amdgcn_fmed3f(r, EPS_F, 1.0f - EPS_F);  // 1-instr clamp
}

// ---- Kernel 2: 1 sample/thread, R0's paired-tree math, DIRECT global stores.
// No LDS, no barrier, no copy-out phase: each thread's 19 results are
// contiguous (out[s*19..s*19+18]); the wave's stores fully cover every 128-B
// line they touch, so L2 write-combining emits full lines. Stores interleave
// with compute (pair tp's stores overlap pair tp+1's FMAs) instead of
// draining in a post-barrier burst — the phase-serialization R10/R11
// implicated. Normal stores (not nt): partial-line dwords must merge in L2.
__global__ __launch_bounds__(BLK) void tree_forward_kernel(
    const float* __restrict__ c20,   // (B, 20)
    const float* __restrict__ w,     // (19, 19) sigmoid'd
    float* __restrict__ out,         // (B, 19)
    int B)
{
    const int tid = threadIdx.x;
    const int s   = blockIdx.x * BLK + tid;
    const bool valid = (s < B);

    // Layer-0 min/max pairs are tree-independent: compute once.
    float mx[10], d[10];
    {
        const v4f* p = reinterpret_cast<const v4f*>(c20 + (size_t)s * 20);
        #pragma unroll
        for (int q = 0; q < 5; ++q) {
            v4f z; z.x = 0.f; z.y = 0.f; z.z = 0.f; z.w = 0.f;
            v4f v = valid ? p[q] : z;
            {
                float mn = fminf(v.x, v.y);
                mx[2*q] = fmaxf(v.x, v.y);
                d[2*q]  = mn - mx[2*q];
            }
            {
                float mn = fminf(v.z, v.w);
                mx[2*q+1] = fmaxf(v.z, v.w);
                d[2*q+1]  = mn - mx[2*q+1];
            }
        }
    }

    float* __restrict__ o = out + (size_t)s * 19;   // per-thread contiguous 76 B

    // 9 tree pairs (R0's proven loop); results stored directly as computed.
    #pragma unroll
    for (int tp = 0; tp < 9; ++tp) {
        const int t0 = 2 * tp, t1 = 2 * tp + 1;
        const float* wr0 = w + t0 * 19;
        const float* wr1 = w + t1 * 19;

        float y0[10], y1[10];
        #pragma unroll
        for (int k = 0; k < 10; ++k) {
            y0[k] = fmaf(wr0[k], d[k], mx[k]);
            y1[k] = fmaf(wr1[k], d[k], mx[k]);
        }

        float z0[5], z1[5];
        #pragma unroll
        for (int k = 0; k < 5; ++k) {
            z0[k] = mixf(y0[2*k], y0[2*k+1], wr0[10 + k]);
            z1[k] = mixf(y1[2*k], y1[2*k+1], wr1[10 + k]);
        }

        float u00 = mixf(z0[0], z0[1], wr0[15]);
        float u01 = mixf(z0[2], z0[3], wr0[16]);
        float u10 = mixf(z1[0], z1[1], wr1[15]);
        float u11 = mixf(z1[2], z1[3], wr1[16]);

        float v0 = mixf(u00, u01, wr0[17]);
        float v1 = mixf(u10, u11, wr1[17]);

        float r0 = mixf(v0, z0[4], wr0[18]);
        float r1 = mixf(v1, z1[4], wr1[18]);

        if (valid) {
            o[t0] = clampf(r0);
            o[t1] = clampf(r1);
        }
    }

    // tree 18 (last, unpaired)
    {
        const float* wr = w + 18 * 19;
        float y[10];
        #pragma unroll
        for (int k = 0; k < 10; ++k)
            y[k] = fmaf(wr[k], d[k], mx[k]);
        float z[5];
        #pragma unroll
        for (int k = 0; k < 5; ++k)
            z[k] = mixf(y[2*k], y[2*k+1], wr[10 + k]);
        float u0 = mixf(z[0], z[1], wr[15]);
        float u1 = mixf(z[2], z[3], wr[16]);
        float v0 = mixf(u0, u1, wr[17]);
        float r  = mixf(v0, z[4], wr[18]);
        if (valid) o[18] = clampf(r);
    }
}

extern "C" void kernel_launch(void* const* d_in, const int* in_sizes, int n_in,
                              void* d_out, int out_size, void* d_ws, size_t ws_size,
                              hipStream_t stream) {
    // setup_inputs order: p1 (B,) int, p2 (B,) int, c20 (B,20) f32, w_raw (19,19) f32
    const float* c20   = (const float*)d_in[2];
    const float* w_raw = (const float*)d_in[3];
    float* out = (float*)d_out;
    float* w   = (float*)d_ws;   // 361 floats of scratch

    int B = in_sizes[0];

    sigmoid_w_kernel<<<1, 384, 0, stream>>>(w_raw, w);

    int grid = (B + BLK - 1) / BLK;
    tree_forward_kernel<<<grid, BLK, 0, stream>>>(c20, w, out, B);
}